// Round 12
// baseline (32809.152 us; speedup 1.0000x reference)
//
#include <hip/hip_runtime.h>

// ---------------------------------------------------------------------------
// NeuralCA fused step, operand-swapped 32x32 MFMA (A = weights, B = pixels):
//   D[chan][pixel] via mfma_f32_32x32x16_bf16. 512-thr blocks (8 waves),
//   2-row blocks, 448 blocks, 2 blocks/CU (69 KB LDS).
//   __launch_bounds__(512,3): cap ~170. R11 used (512,4)=128 and the
//   allocator wholesale-demoted weights/acc to scratch (VGPR=52, 58 MB
//   FETCH/step, 2.9x regression). Empirical rule from R5-R11: cap 128
//   demotes at demand >~70; cap 170 (R10) and cap 256 (R2-R4) never demote.
//   waves 0-3 (G1, chan-quarter wq): h1[32wq..+31][32px pair], K=144 exact
//   waves 4-7 (G23, quarter g):      G2 quarter of pair j-1;
//        waves g<2: G3 (A=W3 LDS, B=h2 LDS) + vectorized epilogue, pair j-2
//   Mailboxes [pixel][chan] (136-short rows): b64 stores (~4-way banked,
//   vs sigma-layout 4B stores' structural 8-way) + natural-order b128 reads.
//   Biases + W3 in LDS (broadcast reads) to keep VGPR demand ~100-120.
// ---------------------------------------------------------------------------

typedef __attribute__((ext_vector_type(8))) short short8;
typedef __attribute__((ext_vector_type(4))) float float4v;
typedef __attribute__((ext_vector_type(16))) float float16v;
typedef __attribute__((ext_vector_type(2))) unsigned uint2v;

#define MFMA32(a, b, c) __builtin_amdgcn_mfma_f32_32x32x16_bf16((a), (b), (c), 0, 0, 0)
#define MFMA16(a, b, c) __builtin_amdgcn_mfma_f32_16x16x32_bf16((a), (b), (c), 0, 0, 0)

__device__ __forceinline__ short f2bf(float f) {
  unsigned u = __builtin_bit_cast(unsigned, f);
  return (short)((u + 0x8000u) >> 16);     // round-half-up
}

__device__ __forceinline__ unsigned pk2bf(float a, float b) {
#if __has_builtin(__builtin_amdgcn_cvt_pk_bf16_f32)
  typedef __attribute__((ext_vector_type(2))) __bf16 bf2;
  bf2 r = __builtin_amdgcn_cvt_pk_bf16_f32(a, b);
  return __builtin_bit_cast(unsigned, r);
#else
  unsigned ua = __builtin_bit_cast(unsigned, a), ub = __builtin_bit_cast(unsigned, b);
  return ((ua + 0x8000u) >> 16) | (((ub + 0x8000u) >> 16) << 16);
#endif
}

__device__ __forceinline__ void async16(const void* g, void* l) {
  __builtin_amdgcn_global_load_lds((const __attribute__((address_space(1))) void*)g,
                                   (__attribute__((address_space(3))) void*)l,
                                   16, 0, 0);
}

// LDS-only barrier (no vmcnt drain - global stores fly free)
__device__ __forceinline__ void sync_lds() {
  asm volatile("s_waitcnt lgkmcnt(0)\n\ts_barrier" ::: "memory");
}

// ---- workspace layout (bytes) ----
#define WS_WE    0          // W_eff [128 out][144 k] bf16, k = off*16 + c
#define WS_W2    36864      // W2    [128][128] bf16 (natural order)
#define WS_W3    69632      // W3    [ 16][128] bf16 (natural order)
#define WS_X32A  73728
#define WS_X32B  12918784
#define WS_X16A  25763840
#define WS_X16B  32186368

// ---------------------------------------------------------------------------
__global__ void prep_x(const float* __restrict__ x, float* __restrict__ x32,
                       short* __restrict__ x16) {
  int i = blockIdx.x * 256 + threadIdx.x;          // exactly 3211264 threads
  int w = i % 224;
  int h = (i / 224) % 224;
  int c = (i / 50176) & 15;
  int bb = i / 802816;
  float v = x[i];
  int o = ((bb * 224 + h) * 224 + w) * 16 + c;     // NHWC
  x32[o] = v;
  x16[o] = f2bf(v);
}

__global__ void prep_w(const float* __restrict__ wp, const float* __restrict__ w1,
                       const float* __restrict__ w2, const float* __restrict__ w3,
                       short* __restrict__ wE, short* __restrict__ w2t,
                       short* __restrict__ w3t) {
  int i = blockIdx.x * 256 + threadIdx.x;          // exactly 36864 threads
  if (i < 18432) {                                  // W_eff [o=128][k=144]
    int o = i / 144, k = i % 144;
    int off = k >> 4, c = k & 15;                   // k = offset*16 + c
    float v = 0.f;
    for (int c3 = 0; c3 < 48; ++c3)
      v += w1[o * 48 + c3] * wp[c3 * 144 + c * 9 + off];
    wE[i] = f2bf(v);
  } else if (i < 34816) {                           // W2 natural
    int j = i - 18432;
    w2t[j] = f2bf(w2[j]);
  } else {                                          // W3 natural
    int j = i - 34816;
    w3t[j] = f2bf(w3[j]);
  }
}

// ---------------------------------------------------------------------------
// One CA step. Block = 2 image rows, 512 threads = 8 waves. 14 pairs of
// 32 consecutive pixels (2 tiles); pipeline over 16 iterations:
//   G1 wave wq:  iter j<14:  h1 chans 32wq..+31 of pair j  -> sBUF[j&1]
//   G23 wave g:  iter 1..14: h2 chans 32g..+31 of pair j-1 -> sH2[j&1]
//   G23 g<2:     iter j>=2:  G3 + epilogue, 16-px half g of pair j-2
template <bool LAST>
__global__ __launch_bounds__(512, 3) void ca_step(
    const short* __restrict__ wEg, const short* __restrict__ w2g,
    const short* __restrict__ w3g, const float* __restrict__ b1,
    const float* __restrict__ b2, const float* __restrict__ xs32,
    const short* __restrict__ xs16, float* __restrict__ xd32,
    short* __restrict__ xd16, float* __restrict__ dout) {
  __shared__ short sXH[4 * 3616];    // 28928 B  halo: 4 rows x 226 x 16ch
  __shared__ short sBUF[2 * 4352];   // 17408 B  h1 [pix 32][chan 128+pad] dbuf
  __shared__ short sH2[2 * 4352];    // 17408 B  h2 same layout, dbuf
  __shared__ short sW3[2048];        //  4096 B  W3 [16][128]
  __shared__ float sB1[128];         //   512 B
  __shared__ float sB2[128];         //   512 B
  // total 68864 B -> 2 blocks/CU; 16 waves/CU = 4/SIMD if VGPR <= 128

  const int tid = threadIdx.x;
  const int lane = tid & 63;
  const int wv = tid >> 6;            // 0..7
  const int nn = lane & 31;           // A: local chan row; B: pixel in pair
  const int kh = lane >> 5;           // k-half (0/1)

  const int blk = blockIdx.x;         // 448 = 4 batches x 112 rowgroups
  const int b = blk / 112;
  const int h0 = (blk % 112) * 2;

  // ---- stage halo: 4 rows x 7 chunks (1KB each); OOB rows -> zeros ----
  const short8 z8 = {0, 0, 0, 0, 0, 0, 0, 0};
  for (int t = wv; t < 28; t += 8) {
    int hr = t / 7, ck = t % 7;
    int hh = h0 - 1 + hr;
    char* l = (char*)sXH + hr * 7232 + 32 + ck * 1024;  // col 0 = image col -1
    if (hh >= 0 && hh < 224) {
      const char* g = (const char*)xs16 + ((size_t)(b * 224 + hh) * 224) * 32 + ck * 1024;
      async16(g + lane * 16, l);
    } else {
      *(short8*)(l + lane * 16) = z8;
    }
  }
  if (tid < 16) {   // zero edge columns (image col -1 and 224) for all 4 rows
    int hr = tid >> 2, wch = tid & 3;
    int colb = (wch < 2) ? 0 : 225;
    *(short8*)((char*)sXH + hr * 7232 + colb * 32 + (wch & 1) * 16) = z8;
  }
  // ---- stage biases + W3 ----
  if (tid < 128) sB1[tid] = b1[tid];
  else if (tid < 256) sB2[tid - 128] = b2[tid - 128];
  for (int i = tid; i < 2048; i += 512) sW3[i] = w3g[i];

  if (wv < 4) {
    // ====== G1 role, chan-quarter wq: conv3x3+MLP1, A = W_eff rows ========
    const int wq = wv;
    short8 wf[9];                     // 36 VGPR: A-frags, K=144 exact
#pragma unroll
    for (int o = 0; o < 9; ++o)
      wf[o] = *(const short8*)(wEg + (32 * wq + nn) * 144 + o * 16 + 8 * kh);

    __syncthreads();                  // staging ready (drains vmcnt)

    for (int j = 0; j < 16; ++j) {
      if (j < 14) {
        const int rr = (2 * j) / 14;
        const int pb = ((2 * j) % 14) * 16;   // 32 consecutive px, one row
        float16v acc;
#pragma unroll
        for (int i = 0; i < 16; ++i) acc[i] = 0.f;
        const int abase = ((rr)*226 + pb + nn) * 16 + 8 * kh;
#pragma unroll 3
        for (int o = 0; o < 9; ++o) {
          int dy = (o * 11) >> 5;     // o/3
          int dx = o - dy * 3;
          short8 bf = *(const short8*)(sXH + abase + (dy * 226 + dx) * 16);
          acc = MFMA32(wf[o], bf, acc);
        }
        // pack: lane holds 16 chans of pixel nn, 4 contiguous groups of 4
        short* dst = sBUF + (j & 1) * 4352 + nn * 136 + 32 * wq + 4 * kh;
#pragma unroll
        for (int G = 0; G < 4; ++G) {
          float4v bv = *(const float4v*)(sB1 + 32 * wq + 8 * G + 4 * kh);
          uint2v pk;
          pk[0] = pk2bf(fmaxf(acc[4 * G + 0] + bv[0], 0.f),
                        fmaxf(acc[4 * G + 1] + bv[1], 0.f));
          pk[1] = pk2bf(fmaxf(acc[4 * G + 2] + bv[2], 0.f),
                        fmaxf(acc[4 * G + 3] + bv[3], 0.f));
          *(uint2v*)(dst + 8 * G) = pk;
        }
      }
      sync_lds();
    }
  } else {
    // ====== G23 role, quarter g: MLP2 (A = W2 rows) + (g<2) MLP3/update ===
    const int g = wv - 4;
    const int c16 = lane & 15;
    const int q = lane >> 4;
    short8 w2f[8];                    // 32 VGPR
#pragma unroll
    for (int u = 0; u < 8; ++u)
      w2f[u] = *(const short8*)(w2g + (32 * g + nn) * 128 + u * 16 + 8 * kh);

    __syncthreads();                  // staging ready

    for (int j = 0; j < 16; ++j) {
      // ---- prefetch residual x (float4) for G3's half-pair ----
      float4v xres;
      size_t pixg = 0;
      int rr3 = 0, pb3 = 0;
      if (g < 2 && j >= 2) {
        rr3 = (2 * (j - 2)) / 14;
        pb3 = ((2 * (j - 2)) % 14) * 16;
        pixg = (size_t)(b * 224 + h0 + rr3) * 224 + pb3 + 16 * g + c16;
        xres = *(const float4v*)(xs32 + pixg * 16 + 4 * q);
      }
      // ---- G2 quarter of pair j-1 ----
      if (j >= 1 && j <= 14) {
        const short* src = sBUF + ((j - 1) & 1) * 4352 + nn * 136 + 8 * kh;
        float16v acc2;
#pragma unroll
        for (int i = 0; i < 16; ++i) acc2[i] = 0.f;
#pragma unroll 2
        for (int u = 0; u < 8; ++u) {
          short8 bf = *(const short8*)(src + u * 16);
          acc2 = MFMA32(w2f[u], bf, acc2);
        }
        short* dst = sH2 + (j & 1) * 4352 + nn * 136 + 32 * g + 4 * kh;
#pragma unroll
        for (int G = 0; G < 4; ++G) {
          float4v bv = *(const float4v*)(sB2 + 32 * g + 8 * G + 4 * kh);
          uint2v pk;
          pk[0] = pk2bf(fmaxf(acc2[4 * G + 0] + bv[0], 0.f),
                        fmaxf(acc2[4 * G + 1] + bv[1], 0.f));
          pk[1] = pk2bf(fmaxf(acc2[4 * G + 2] + bv[2], 0.f),
                        fmaxf(acc2[4 * G + 3] + bv[3], 0.f));
          *(uint2v*)(dst + 8 * G) = pk;
        }
      }
      // ---- G3 + epilogue, 16-px half g of pair j-2 ----
      if (g < 2 && j >= 2) {
        const short* sh = sH2 + ((j - 1) & 1) * 4352 + (16 * g + c16) * 136;
        float4v acc3 = (float4v){0.f, 0.f, 0.f, 0.f};
#pragma unroll
        for (int kc = 0; kc < 4; ++kc) {
          short8 af = *(const short8*)(sW3 + c16 * 128 + kc * 32 + q * 8);
          short8 bf = *(const short8*)(sh + kc * 32 + q * 8);
          acc3 = MFMA16(af, bf, acc3);  // D[chan 4q+r][pixel c16]
        }
        float vo[4];
#pragma unroll
        for (int r = 0; r < 4; ++r)
          vo[r] = fminf(fmaxf(xres[r] + acc3[r], 0.f), 1.f);
        if (LAST) {
#pragma unroll
          for (int r = 0; r < 4; ++r)
            dout[((size_t)(b * 16 + 4 * q + r) * 224 + h0 + rr3) * 224 +
                 pb3 + 16 * g + c16] = vo[r];
        } else {
          *(float4v*)(xd32 + pixg * 16 + 4 * q) =
              (float4v){vo[0], vo[1], vo[2], vo[3]};
          uint2v p16;
          p16[0] = pk2bf(vo[0], vo[1]);
          p16[1] = pk2bf(vo[2], vo[3]);
          *(uint2v*)(xd16 + pixg * 16 + 4 * q) = p16;
        }
      }
      sync_lds();
    }
  }
}

// ---------------------------------------------------------------------------
extern "C" void kernel_launch(void* const* d_in, const int* in_sizes, int n_in,
                              void* d_out, int out_size, void* d_ws, size_t ws_size,
                              hipStream_t stream) {
  const float* x  = (const float*)d_in[0];
  const float* wp = (const float*)d_in[1];
  const float* w1 = (const float*)d_in[2];
  const float* b1 = (const float*)d_in[3];
  const float* w2 = (const float*)d_in[4];
  const float* b2 = (const float*)d_in[5];
  const float* w3 = (const float*)d_in[6];

  char* ws = (char*)d_ws;
  short* wEg = (short*)(ws + WS_WE);
  short* w2g = (short*)(ws + WS_W2);
  short* w3g = (short*)(ws + WS_W3);
  float* X32[2] = {(float*)(ws + WS_X32A), (float*)(ws + WS_X32B)};
  short* X16[2] = {(short*)(ws + WS_X16A), (short*)(ws + WS_X16B)};

  prep_x<<<12544, 256, 0, stream>>>(x, X32[0], X16[0]);
  prep_w<<<144, 256, 0, stream>>>(wp, w1, w2, w3, wEg, w2g, w3g);

  for (int s = 0; s < 39; ++s) {
    int sb = s & 1;
    ca_step<false><<<448, 512, 0, stream>>>(wEg, w2g, w3g, b1, b2,
                                            X32[sb], X16[sb],
                                            X32[1 - sb], X16[1 - sb], nullptr);
  }
  ca_step<true><<<448, 512, 0, stream>>>(wEg, w2g, w3g, b1, b2,
                                         X32[1], X16[1],
                                         X32[0], X16[0], (float*)d_out);
}

// Round 13
// 1026.728 us; speedup vs baseline: 31.9551x; 31.9551x over previous
//
#include <hip/hip_runtime.h>

// ---------------------------------------------------------------------------
// NeuralCA fused step, operand-swapped 32x32 MFMA (A = weights, B = pixels).
//   D[chan][pixel] via mfma_f32_32x32x16_bf16. 512-thr blocks (8 waves),
//   2-row blocks, 448 blocks. __launch_bounds__(512,2) -> cap 256.
//   DEMOTION POSTMORTEM (R5-R12): two mechanisms put weight arrays in scratch:
//    (1) partial unroll (#pragma unroll N<full) -> runtime-indexed array ->
//        SROA fails -> scratch at ANY cap (R11: 74us/step, R12: 820us/step);
//    (2) demand > launch_bounds cap -> wholesale spill (R8: cap 128).
//   Fix: FULL unrolls only + cap 256. Occupancy then follows actual VGPR:
//   <=128 -> 2 blocks/CU (66.8 KB LDS each), 16 waves/CU.
//   waves 0-3 (G1, chan-quarter wq): h1[32wq..+31][32px pair j], K=144 exact
//   waves 4-7 (G23, quarter g):      G2 quarter of pair j-1 -> sH2;
//        waves g<2: G3 (A=W3 LDS, B=h2 LDS) + float4 epilogue, pair j-2
//   Mailboxes XOR-swizzled ([pix 32][128 shorts], 16B slot = grp^(pix&15)):
//   stores & G2 reads <=2-way bank aliasing (free per m136).
// ---------------------------------------------------------------------------

typedef __attribute__((ext_vector_type(8))) short short8;
typedef __attribute__((ext_vector_type(4))) float float4v;
typedef __attribute__((ext_vector_type(16))) float float16v;
typedef __attribute__((ext_vector_type(2))) unsigned uint2v;

#define MFMA32(a, b, c) __builtin_amdgcn_mfma_f32_32x32x16_bf16((a), (b), (c), 0, 0, 0)
#define MFMA16(a, b, c) __builtin_amdgcn_mfma_f32_16x16x32_bf16((a), (b), (c), 0, 0, 0)

__device__ __forceinline__ short f2bf(float f) {
  unsigned u = __builtin_bit_cast(unsigned, f);
  return (short)((u + 0x8000u) >> 16);     // round-half-up
}

__device__ __forceinline__ unsigned pk2bf(float a, float b) {
#if __has_builtin(__builtin_amdgcn_cvt_pk_bf16_f32)
  typedef __attribute__((ext_vector_type(2))) __bf16 bf2;
  bf2 r = __builtin_amdgcn_cvt_pk_bf16_f32(a, b);
  return __builtin_bit_cast(unsigned, r);
#else
  unsigned ua = __builtin_bit_cast(unsigned, a), ub = __builtin_bit_cast(unsigned, b);
  return ((ua + 0x8000u) >> 16) | (((ub + 0x8000u) >> 16) << 16);
#endif
}

__device__ __forceinline__ void async16(const void* g, void* l) {
  __builtin_amdgcn_global_load_lds((const __attribute__((address_space(1))) void*)g,
                                   (__attribute__((address_space(3))) void*)l,
                                   16, 0, 0);
}

// LDS-only barrier (no vmcnt drain - global stores fly free)
__device__ __forceinline__ void sync_lds() {
  asm volatile("s_waitcnt lgkmcnt(0)\n\ts_barrier" ::: "memory");
}

// ---- workspace layout (bytes) ----
#define WS_WE    0          // W_eff [128 out][144 k] bf16, k = off*16 + c
#define WS_W2    36864      // W2    [128][128] bf16 (natural order)
#define WS_W3    69632      // W3    [ 16][128] bf16 (natural order)
#define WS_X32A  73728
#define WS_X32B  12918784
#define WS_X16A  25763840
#define WS_X16B  32186368

// ---------------------------------------------------------------------------
__global__ void prep_x(const float* __restrict__ x, float* __restrict__ x32,
                       short* __restrict__ x16) {
  int i = blockIdx.x * 256 + threadIdx.x;          // exactly 3211264 threads
  int w = i % 224;
  int h = (i / 224) % 224;
  int c = (i / 50176) & 15;
  int bb = i / 802816;
  float v = x[i];
  int o = ((bb * 224 + h) * 224 + w) * 16 + c;     // NHWC
  x32[o] = v;
  x16[o] = f2bf(v);
}

__global__ void prep_w(const float* __restrict__ wp, const float* __restrict__ w1,
                       const float* __restrict__ w2, const float* __restrict__ w3,
                       short* __restrict__ wE, short* __restrict__ w2t,
                       short* __restrict__ w3t) {
  int i = blockIdx.x * 256 + threadIdx.x;          // exactly 36864 threads
  if (i < 18432) {                                  // W_eff [o=128][k=144]
    int o = i / 144, k = i % 144;
    int off = k >> 4, c = k & 15;                   // k = offset*16 + c
    float v = 0.f;
    for (int c3 = 0; c3 < 48; ++c3)
      v += w1[o * 48 + c3] * wp[c3 * 144 + c * 9 + off];
    wE[i] = f2bf(v);
  } else if (i < 34816) {                           // W2 natural
    int j = i - 18432;
    w2t[j] = f2bf(w2[j]);
  } else {                                          // W3 natural
    int j = i - 34816;
    w3t[j] = f2bf(w3[j]);
  }
}

// ---------------------------------------------------------------------------
// One CA step. Block = 2 image rows, 512 threads = 8 waves. 14 pairs of
// 32 consecutive pixels; pipeline over 16 iterations:
//   G1 wave wq:  iter j<14:  h1 chans 32wq..+31 of pair j  -> sBUF[j&1]
//   G23 wave g:  iter 1..14: h2 chans 32g..+31 of pair j-1 -> sH2[j&1]
//   G23 g<2:     iter j>=2:  G3 + epilogue, 16-px half g of pair j-2
template <bool LAST>
__global__ __launch_bounds__(512, 2) void ca_step(
    const short* __restrict__ wEg, const short* __restrict__ w2g,
    const short* __restrict__ w3g, const float* __restrict__ b1,
    const float* __restrict__ b2, const float* __restrict__ xs32,
    const short* __restrict__ xs16, float* __restrict__ xd32,
    short* __restrict__ xd16, float* __restrict__ dout) {
  __shared__ short sXH[4 * 3616];    // 28928 B  halo: 4 rows x 226 x 16ch
  __shared__ short sBUF[2 * 4096];   // 16384 B  h1 [pix32][128] swizzled, dbuf
  __shared__ short sH2[2 * 4096];    // 16384 B  h2 same, dbuf
  __shared__ short sW3[2048];        //  4096 B  W3 [16][128] swizzled
  __shared__ float sB1[128];         //   512 B
  __shared__ float sB2[128];         //   512 B
  // total 66816 B -> 2 blocks/CU if VGPR <= 128

  const int tid = threadIdx.x;
  const int lane = tid & 63;
  const int wv = tid >> 6;            // 0..7
  const int nn = lane & 31;           // A: local chan row; B: pixel in pair
  const int kh = lane >> 5;           // k-half (0/1)

  const int blk = blockIdx.x;         // 448 = 4 batches x 112 rowgroups
  const int b = blk / 112;
  const int h0 = (blk % 112) * 2;

  // ---- stage halo: 4 rows x 7 chunks (1KB each); OOB rows -> zeros ----
  const short8 z8 = {0, 0, 0, 0, 0, 0, 0, 0};
  for (int t = wv; t < 28; t += 8) {
    int hr = t / 7, ck = t % 7;
    int hh = h0 - 1 + hr;
    char* l = (char*)sXH + hr * 7232 + 32 + ck * 1024;  // col 0 = image col -1
    if (hh >= 0 && hh < 224) {
      const char* g = (const char*)xs16 + ((size_t)(b * 224 + hh) * 224) * 32 + ck * 1024;
      async16(g + lane * 16, l);
    } else {
      *(short8*)(l + lane * 16) = z8;
    }
  }
  if (tid < 16) {   // zero edge columns (image col -1 and 224) for all 4 rows
    int hr = tid >> 2, wch = tid & 3;
    int colb = (wch < 2) ? 0 : 225;
    *(short8*)((char*)sXH + hr * 7232 + colb * 32 + (wch & 1) * 16) = z8;
  }
  // ---- stage biases + W3 (swizzled: slot = grp ^ row) ----
  if (tid < 128) sB1[tid] = b1[tid];
  else if (tid < 256) sB2[tid - 128] = b2[tid - 128];
  for (int i = tid; i < 2048; i += 512) {
    int row = i >> 7, col = i & 127;
    int grp = col >> 3, win = col & 7;
    sW3[(row << 7) + ((grp ^ row) << 3) + win] = w3g[i];
  }

  if (wv < 4) {
    // ====== G1 role, chan-quarter wq: conv3x3+MLP1, A = W_eff rows ========
    const int wq = wv;
    short8 wf[9];                     // 36 VGPR: A-frags, K=144 exact
#pragma unroll
    for (int o = 0; o < 9; ++o)
      wf[o] = *(const short8*)(wEg + (32 * wq + nn) * 144 + o * 16 + 8 * kh);

    __syncthreads();                  // staging ready (drains vmcnt)

    for (int j = 0; j < 16; ++j) {
      if (j < 14) {
        const int rr = (2 * j) / 14;
        const int pb = ((2 * j) % 14) * 16;   // 32 consecutive px, one row
        float16v acc;
#pragma unroll
        for (int i = 0; i < 16; ++i) acc[i] = 0.f;
        const int abase = (rr * 226 + pb + nn) * 16 + 8 * kh;
#pragma unroll
        for (int o = 0; o < 9; ++o) {
          const int dy = o / 3, dx = o % 3;
          short8 bf = *(const short8*)(sXH + abase + (dy * 226 + dx) * 16);
          acc = MFMA32(wf[o], bf, acc);
        }
        // pack: lane holds 16 chans of pixel nn; swizzled b64 stores
        short* dst = sBUF + (j & 1) * 4096 + nn * 128 + 4 * kh;
#pragma unroll
        for (int G = 0; G < 4; ++G) {
          float4v bv = *(const float4v*)(sB1 + 32 * wq + 8 * G + 4 * kh);
          uint2v pk;
          pk[0] = pk2bf(fmaxf(acc[4 * G + 0] + bv[0], 0.f),
                        fmaxf(acc[4 * G + 1] + bv[1], 0.f));
          pk[1] = pk2bf(fmaxf(acc[4 * G + 2] + bv[2], 0.f),
                        fmaxf(acc[4 * G + 3] + bv[3], 0.f));
          *(uint2v*)(dst + (((4 * wq + G) ^ (nn & 15)) << 3)) = pk;
        }
      }
      sync_lds();
    }
  } else {
    // ====== G23 role, quarter g: MLP2 (A = W2 rows) + (g<2) MLP3/update ===
    const int g = wv - 4;
    const int c16 = lane & 15;
    const int q = lane >> 4;
    short8 w2f[8];                    // 32 VGPR
#pragma unroll
    for (int u = 0; u < 8; ++u)
      w2f[u] = *(const short8*)(w2g + (32 * g + nn) * 128 + u * 16 + 8 * kh);

    __syncthreads();                  // staging ready

    for (int j = 0; j < 16; ++j) {
      // ---- prefetch residual x (float4) for G3's half-pair ----
      float4v xres;
      size_t pixg = 0;
      int rr3 = 0, pb3 = 0;
      if (g < 2 && j >= 2) {
        rr3 = (2 * (j - 2)) / 14;
        pb3 = ((2 * (j - 2)) % 14) * 16;
        pixg = (size_t)(b * 224 + h0 + rr3) * 224 + pb3 + 16 * g + c16;
        xres = *(const float4v*)(xs32 + pixg * 16 + 4 * q);
      }
      // ---- G2 quarter of pair j-1 (swizzled b128 reads) ----
      if (j >= 1 && j <= 14) {
        const short* src = sBUF + ((j - 1) & 1) * 4096 + nn * 128;
        float16v acc2;
#pragma unroll
        for (int i = 0; i < 16; ++i) acc2[i] = 0.f;
#pragma unroll
        for (int u = 0; u < 8; ++u) {
          short8 bf = *(const short8*)(src + (((2 * u + kh) ^ (nn & 15)) << 3));
          acc2 = MFMA32(w2f[u], bf, acc2);
        }
        short* dst = sH2 + (j & 1) * 4096 + nn * 128 + 4 * kh;
#pragma unroll
        for (int G = 0; G < 4; ++G) {
          float4v bv = *(const float4v*)(sB2 + 32 * g + 8 * G + 4 * kh);
          uint2v pk;
          pk[0] = pk2bf(fmaxf(acc2[4 * G + 0] + bv[0], 0.f),
                        fmaxf(acc2[4 * G + 1] + bv[1], 0.f));
          pk[1] = pk2bf(fmaxf(acc2[4 * G + 2] + bv[2], 0.f),
                        fmaxf(acc2[4 * G + 3] + bv[3], 0.f));
          *(uint2v*)(dst + (((4 * g + G) ^ (nn & 15)) << 3)) = pk;
        }
      }
      // ---- G3 + epilogue, 16-px half g of pair j-2 ----
      if (g < 2 && j >= 2) {
        const short* sh = sH2 + ((j - 1) & 1) * 4096 + (16 * g + c16) * 128;
        float4v acc3 = (float4v){0.f, 0.f, 0.f, 0.f};
#pragma unroll
        for (int kc = 0; kc < 4; ++kc) {
          short8 af = *(const short8*)(sW3 + c16 * 128 + (((4 * kc + q) ^ c16) << 3));
          short8 bf = *(const short8*)(sh + (((4 * kc + q) ^ c16) << 3));
          acc3 = MFMA16(af, bf, acc3);  // D[chan 4q+r][pixel c16]
        }
        float vo[4];
#pragma unroll
        for (int r = 0; r < 4; ++r)
          vo[r] = fminf(fmaxf(xres[r] + acc3[r], 0.f), 1.f);
        if (LAST) {
#pragma unroll
          for (int r = 0; r < 4; ++r)
            dout[((size_t)(b * 16 + 4 * q + r) * 224 + h0 + rr3) * 224 +
                 pb3 + 16 * g + c16] = vo[r];
        } else {
          *(float4v*)(xd32 + pixg * 16 + 4 * q) =
              (float4v){vo[0], vo[1], vo[2], vo[3]};
          uint2v p16;
          p16[0] = pk2bf(vo[0], vo[1]);
          p16[1] = pk2bf(vo[2], vo[3]);
          *(uint2v*)(xd16 + pixg * 16 + 4 * q) = p16;
        }
      }
      sync_lds();
    }
  }
}

// ---------------------------------------------------------------------------
extern "C" void kernel_launch(void* const* d_in, const int* in_sizes, int n_in,
                              void* d_out, int out_size, void* d_ws, size_t ws_size,
                              hipStream_t stream) {
  const float* x  = (const float*)d_in[0];
  const float* wp = (const float*)d_in[1];
  const float* w1 = (const float*)d_in[2];
  const float* b1 = (const float*)d_in[3];
  const float* w2 = (const float*)d_in[4];
  const float* b2 = (const float*)d_in[5];
  const float* w3 = (const float*)d_in[6];

  char* ws = (char*)d_ws;
  short* wEg = (short*)(ws + WS_WE);
  short* w2g = (short*)(ws + WS_W2);
  short* w3g = (short*)(ws + WS_W3);
  float* X32[2] = {(float*)(ws + WS_X32A), (float*)(ws + WS_X32B)};
  short* X16[2] = {(short*)(ws + WS_X16A), (short*)(ws + WS_X16B)};

  prep_x<<<12544, 256, 0, stream>>>(x, X32[0], X16[0]);
  prep_w<<<144, 256, 0, stream>>>(wp, w1, w2, w3, wEg, w2g, w3g);

  for (int s = 0; s < 39; ++s) {
    int sb = s & 1;
    ca_step<false><<<448, 512, 0, stream>>>(wEg, w2g, w3g, b1, b2,
                                            X32[sb], X16[sb],
                                            X32[1 - sb], X16[1 - sb], nullptr);
  }
  ca_step<true><<<448, 512, 0, stream>>>(wEg, w2g, w3g, b1, b2,
                                         X32[1], X16[1],
                                         X32[0], X16[0], (float*)d_out);
}